// Round 11
// baseline (96.924 us; speedup 1.0000x reference)
//
#include <hip/hip_runtime.h>
#include <math.h>

// Problem constants (reference: BATCH=4096, DIM=512, sigma = s*I).
#define NB 4096
#define ND 512
#define TILE 128                   // block tile (2x2 waves of 64x64)
#define NCP 8                      // 8 chunk-pairs (16 k-chunks of 32)

typedef float floatx4 __attribute__((ext_vector_type(4)));
typedef long longx2 __attribute__((ext_vector_type(2)));
typedef unsigned int uint;

// ---------------------------------------------------------------------------
// fp8 e4m3fn (OCP) software convert. Decode matches HW MFMA semantics exactly
// (so hq computed from decoded values makes the Gram diagonal exactly ~0);
// encode rounding flavor is irrelevant to correctness (margin ~400 in expo).
// ---------------------------------------------------------------------------
__device__ inline unsigned char enc_e4m3(float x) {
    unsigned bits = __float_as_uint(x);
    unsigned sign = (bits >> 31) << 7;
    float ax = fabsf(x);
    if (ax < 0.015625f) {                       // below 2^-6: fp8 subnormal
        int m = (int)(ax * 512.0f + 0.5f);      // 0..8 (8 -> min normal)
        return (unsigned char)(sign | m);
    }
    int e = (int)((bits >> 23) & 0xFF) - 127;   // >= -6 here
    unsigned r = ((bits & 0x7FFFFF) + 0x80000) >> 20;  // round to 3 mant bits
    if (r == 8) { r = 0; e += 1; }
    if (e > 8) { e = 8; r = 7; }                // clamp to 448 (paranoia)
    return (unsigned char)(sign | ((unsigned)(e + 7) << 3) | r);
}

__device__ inline float dec_e4m3(unsigned char b) {
    int e = (b >> 3) & 0xF;
    int m = b & 7;
    float mag = e ? ldexpf(1.0f + (float)m * 0.125f, e - 7)
                  : ldexpf((float)m * 0.125f, -6);
    return (b & 0x80) ? -mag : mag;
}

// ---------------------------------------------------------------------------
// Panel-pair layout (fragment-native fp8): 16B unit index
//   u = ((row>>4)*8 + cp)*64 + sub*16 + (row&15)
// holds, for chunk-pair cp (chunks 2cp,2cp+1), the 8-byte A/B fragments of
// (row&15, k-subchunk sub) — low 8B = chunk 2cp, high 8B = chunk 2cp+1.
// A wave's fragment load for (panel, cp) is base + lane*16B: one coalesced
// 1KB global_load_dwordx4 already in mfma_f32_16x16x32_fp8_fp8 layout
// (lane: row=lane&15, sub=lane>>4), covering TWO k-chunks. No LDS/barriers.
// ---------------------------------------------------------------------------

// Kernel 1: cast mu -> fp8 panels (one wave per row; lane l covers k in
// [8l,8l+8)), hq[i] = 0.5*sum(dec(enc(x))^2), zero sumexp.
__global__ __launch_bounds__(256) void prep_kernel(const float* __restrict__ mu,
                                                   unsigned char* __restrict__ muf8,
                                                   float* __restrict__ hq,
                                                   float* __restrict__ sumexp) {
    const int t = threadIdx.x;
    const int wave = t >> 6, lane = t & 63;
    const int row = blockIdx.x * 4 + wave;
    const float4* src = (const float4*)(mu + (size_t)row * ND) + lane * 2;
    const float4 v0 = src[0], v1 = src[1];
    unsigned char b[8];
    b[0] = enc_e4m3(v0.x); b[1] = enc_e4m3(v0.y);
    b[2] = enc_e4m3(v0.z); b[3] = enc_e4m3(v0.w);
    b[4] = enc_e4m3(v1.x); b[5] = enc_e4m3(v1.y);
    b[6] = enc_e4m3(v1.z); b[7] = enc_e4m3(v1.w);
    uint lo = (uint)b[0] | ((uint)b[1] << 8) | ((uint)b[2] << 16) | ((uint)b[3] << 24);
    uint hi = (uint)b[4] | ((uint)b[5] << 8) | ((uint)b[6] << 16) | ((uint)b[7] << 24);
    // lane l: pair cp = l>>3, half h = (l>>2)&1, sub = l&3.
    const size_t unit = ((size_t)(row >> 4) * 8 + (lane >> 3)) * 64
                      + (size_t)(lane & 3) * 16 + (row & 15);
    uint2 pk; pk.x = lo; pk.y = hi;
    *(uint2*)(muf8 + unit * 16 + ((lane >> 2) & 1) * 8) = pk;
    float sq = 0.0f;
    #pragma unroll
    for (int e = 0; e < 8; e++) { float f = dec_e4m3(b[e]); sq += f * f; }
    #pragma unroll
    for (int off = 32; off > 0; off >>= 1) sq += __shfl_down(sq, off, 64);
    if (lane == 0) {
        hq[row] = 0.5f * sq;
        sumexp[row] = 0.0f;
    }
}

// Kernel 2: barrier-free, LDS-free fp8 Gram + exp + row-sum scatter.
// 128x128 block tile, each wave a 64x64 quadrant (4x4 16x16 accs).
// Fragments loaded straight from panel-layout muf8 (coalesced 1KB
// wave-loads already in MFMA layout), 3-buffer register pipeline at
// PREFETCH DISTANCE 3 (consume cp, then overwrite that buffer with cp+3)
// — covers ~3 chunk-pairs of MFMA issue per in-flight load, spanning
// L3-hit latency on the compulsory per-XCD fills. VGPR must stay <= 128
// to keep 4 waves/SIMD. XCD-aware swizzle keeps each XCD's working set
// (~1.5 MB) L2-resident. NO fences (agent-scope release emits buffer_wbl2
// -> L2 eviction poison, proven R2+R9).
// expo[i,j] = (G_ij - hq_i - hq_j)/s <= ~0 (max on diag = 0): plain
// sum-of-exp, no online max needed.
__global__ __launch_bounds__(256) void gram_lse_kernel(const unsigned char* __restrict__ muf8,
                                                       const float* __restrict__ hq,
                                                       const float* __restrict__ sigma,
                                                       float* __restrict__ sumexp) {
    const int t = threadIdx.x;
    const int wave = t >> 6;
    const int lane = t & 63;
    const int r16 = lane & 15;
    const int quad = lane >> 4;

    // XCD swizzle: x = XCD, s = slot; region = 16 tile-rows x 8 tile-cols.
    const int bswz = blockIdx.x;
    const int x = bswz & 7, s = bswz >> 3;
    const int by = (x >> 2) * 16 + (s & 15);
    const int bx = (x & 3) * 8 + (s >> 4);

    const int row0 = by * TILE + (wave >> 1) * 64;
    const int col0 = bx * TILE + (wave & 1) * 64;

    // Per-fragment base pointers (16B units): panel p, cp=0, this lane.
    const longx2* base = (const longx2*)muf8;
    const longx2* pA[4];
    const longx2* pB[4];
    #pragma unroll
    for (int i = 0; i < 4; i++)
        pA[i] = base + ((size_t)(row0 / 16 + i) * 8) * 64 + lane;
    #pragma unroll
    for (int j = 0; j < 4; j++)
        pB[j] = base + ((size_t)(col0 / 16 + j) * 8) * 64 + lane;

    floatx4 acc[4][4];
    #pragma unroll
    for (int i = 0; i < 4; i++)
        #pragma unroll
        for (int j = 0; j < 4; j++) {
            floatx4 z = {0.f, 0.f, 0.f, 0.f};
            acc[i][j] = z;
        }

    // 3-buffer register pipeline, prefetch distance 3 (cp stride = 64 units).
    longx2 fa[3][4], fb[3][4];
    #pragma unroll
    for (int u = 0; u < 3; u++) {
        #pragma unroll
        for (int i = 0; i < 4; i++) fa[u][i] = pA[i][u * 64];
        #pragma unroll
        for (int j = 0; j < 4; j++) fb[u][j] = pB[j][u * 64];
    }

    #pragma unroll
    for (int cp = 0; cp < NCP; cp++) {
        const int cur = cp % 3;
        #pragma unroll
        for (int i = 0; i < 4; i++)
            #pragma unroll
            for (int j = 0; j < 4; j++)
                acc[i][j] = __builtin_amdgcn_mfma_f32_16x16x32_fp8_fp8(fa[cur][i][0], fb[cur][j][0], acc[i][j], 0, 0, 0);
        #pragma unroll
        for (int i = 0; i < 4; i++)
            #pragma unroll
            for (int j = 0; j < 4; j++)
                acc[i][j] = __builtin_amdgcn_mfma_f32_16x16x32_fp8_fp8(fa[cur][i][1], fb[cur][j][1], acc[i][j], 0, 0, 0);
        if (cp + 3 < NCP) {
            #pragma unroll
            for (int i = 0; i < 4; i++) fa[cur][i] = pA[i][(cp + 3) * 64];
            #pragma unroll
            for (int j = 0; j < 4; j++) fb[cur][j] = pB[j][(cp + 3) * 64];
        }
    }

    // Epilogue. C/D layout (m89-verified, dtype-independent): col = lane&15,
    // row = quad*4 + reg.
    const float inv_s = 1.0f / sigma[0];
    float hqc[4];
    #pragma unroll
    for (int j = 0; j < 4; j++) hqc[j] = hq[col0 + j * 16 + r16];

    #pragma unroll
    for (int i = 0; i < 4; i++) {
        #pragma unroll
        for (int r = 0; r < 4; r++) {
            const int row = row0 + i * 16 + quad * 4 + r;
            const float hr = hq[row];
            float rs = 0.0f;
            #pragma unroll
            for (int j = 0; j < 4; j++)
                rs += __expf((acc[i][j][r] - hr - hqc[j]) * inv_s);
            rs += __shfl_xor(rs, 1, 64);
            rs += __shfl_xor(rs, 2, 64);
            rs += __shfl_xor(rs, 4, 64);
            rs += __shfl_xor(rs, 8, 64);
            if (r16 == 0) atomicAdd(&sumexp[row], rs);
        }
    }
}

// Kernel 3: entropy = D/2 + ln(B) + (D/2)ln(2*pi*s) - mean_i log(sumexp_i)
__global__ __launch_bounds__(1024) void finalize_kernel(const float* __restrict__ sumexp,
                                                        const float* __restrict__ sigma,
                                                        float* __restrict__ out) {
    const int t = threadIdx.x;
    float local = 0.0f;
    for (int i = t; i < NB; i += 1024) local += logf(sumexp[i]);
    #pragma unroll
    for (int off = 32; off > 0; off >>= 1) local += __shfl_down(local, off, 64);
    __shared__ float red[16];
    if ((t & 63) == 0) red[t >> 6] = local;
    __syncthreads();
    if (t == 0) {
        double tot = 0.0;
        #pragma unroll
        for (int i = 0; i < 16; i++) tot += (double)red[i];
        const double s = (double)sigma[0];
        const double ent = (double)(ND / 2)
                         + log((double)NB)
                         + (double)(ND / 2) * log(2.0 * M_PI * s)
                         - tot / (double)NB;
        out[0] = (float)ent;
        out[1] = (float)ent;
    }
}

extern "C" void kernel_launch(void* const* d_in, const int* in_sizes, int n_in,
                              void* d_out, int out_size, void* d_ws, size_t ws_size,
                              hipStream_t stream) {
    (void)in_sizes; (void)n_in; (void)out_size; (void)ws_size;
    const float* codewords = (const float*)d_in[1];  // d_in[0] = info (unused)
    const float* sigma     = (const float*)d_in[2];
    float* out = (float*)d_out;

    char* ws = (char*)d_ws;
    unsigned char* muf8 = (unsigned char*)ws;                      // 2 MB (fp8 panels)
    float* hq     = (float*)(ws + (size_t)NB * ND);                // 16 KB
    float* sumexp = hq + NB;                                       // 16 KB

    prep_kernel<<<NB / 4, 256, 0, stream>>>(codewords, muf8, hq, sumexp);
    gram_lse_kernel<<<1024, 256, 0, stream>>>(muf8, hq, sigma, sumexp);
    finalize_kernel<<<1, 1024, 0, stream>>>(sumexp, sigma, out);
}

// Round 12
// 92.985 us; speedup vs baseline: 1.0424x; 1.0424x over previous
//
#include <hip/hip_runtime.h>
#include <math.h>

// Problem constants (reference: BATCH=4096, DIM=512, sigma = s*I).
#define NB 4096
#define ND 512
#define TILE 128                   // block tile (2x2 waves of 64x64)
#define NCP 8                      // 8 chunk-pairs (16 k-chunks of 32)

typedef float floatx4 __attribute__((ext_vector_type(4)));
typedef long longx2 __attribute__((ext_vector_type(2)));
typedef unsigned int uint;

// ---------------------------------------------------------------------------
// fp8 e4m3fn (OCP) software convert. Decode matches HW MFMA semantics exactly
// (so hq computed from decoded values makes the Gram diagonal exactly ~0);
// encode rounding flavor is irrelevant to correctness (margin ~400 in expo).
// ---------------------------------------------------------------------------
__device__ inline unsigned char enc_e4m3(float x) {
    unsigned bits = __float_as_uint(x);
    unsigned sign = (bits >> 31) << 7;
    float ax = fabsf(x);
    if (ax < 0.015625f) {                       // below 2^-6: fp8 subnormal
        int m = (int)(ax * 512.0f + 0.5f);      // 0..8 (8 -> min normal)
        return (unsigned char)(sign | m);
    }
    int e = (int)((bits >> 23) & 0xFF) - 127;   // >= -6 here
    unsigned r = ((bits & 0x7FFFFF) + 0x80000) >> 20;  // round to 3 mant bits
    if (r == 8) { r = 0; e += 1; }
    if (e > 8) { e = 8; r = 7; }                // clamp to 448 (paranoia)
    return (unsigned char)(sign | ((unsigned)(e + 7) << 3) | r);
}

__device__ inline float dec_e4m3(unsigned char b) {
    int e = (b >> 3) & 0xF;
    int m = b & 7;
    float mag = e ? ldexpf(1.0f + (float)m * 0.125f, e - 7)
                  : ldexpf((float)m * 0.125f, -6);
    return (b & 0x80) ? -mag : mag;
}

// ---------------------------------------------------------------------------
// Panel-pair layout (fragment-native fp8): 16B unit index
//   u = ((row>>4)*8 + cp)*64 + sub*16 + (row&15)
// holds, for chunk-pair cp (chunks 2cp,2cp+1), the 8-byte A/B fragments of
// (row&15, k-subchunk sub) — low 8B = chunk 2cp, high 8B = chunk 2cp+1.
// A wave's fragment load for (panel, cp) is base + lane*16B: one coalesced
// 1KB global_load_dwordx4 already in mfma_f32_16x16x32_fp8_fp8 layout
// (lane: row=lane&15, sub=lane>>4), covering TWO k-chunks. No LDS/barriers.
// ---------------------------------------------------------------------------

// Kernel 1: cast mu -> fp8 panels (one wave per row; lane l covers k in
// [8l,8l+8)), hq[i] = 0.5*sum(dec(enc(x))^2), zero sumexp.
__global__ __launch_bounds__(256) void prep_kernel(const float* __restrict__ mu,
                                                   unsigned char* __restrict__ muf8,
                                                   float* __restrict__ hq,
                                                   float* __restrict__ sumexp) {
    const int t = threadIdx.x;
    const int wave = t >> 6, lane = t & 63;
    const int row = blockIdx.x * 4 + wave;
    const float4* src = (const float4*)(mu + (size_t)row * ND) + lane * 2;
    const float4 v0 = src[0], v1 = src[1];
    unsigned char b[8];
    b[0] = enc_e4m3(v0.x); b[1] = enc_e4m3(v0.y);
    b[2] = enc_e4m3(v0.z); b[3] = enc_e4m3(v0.w);
    b[4] = enc_e4m3(v1.x); b[5] = enc_e4m3(v1.y);
    b[6] = enc_e4m3(v1.z); b[7] = enc_e4m3(v1.w);
    uint lo = (uint)b[0] | ((uint)b[1] << 8) | ((uint)b[2] << 16) | ((uint)b[3] << 24);
    uint hi = (uint)b[4] | ((uint)b[5] << 8) | ((uint)b[6] << 16) | ((uint)b[7] << 24);
    // lane l: pair cp = l>>3, half h = (l>>2)&1, sub = l&3.
    const size_t unit = ((size_t)(row >> 4) * 8 + (lane >> 3)) * 64
                      + (size_t)(lane & 3) * 16 + (row & 15);
    uint2 pk; pk.x = lo; pk.y = hi;
    *(uint2*)(muf8 + unit * 16 + ((lane >> 2) & 1) * 8) = pk;
    float sq = 0.0f;
    #pragma unroll
    for (int e = 0; e < 8; e++) { float f = dec_e4m3(b[e]); sq += f * f; }
    #pragma unroll
    for (int off = 32; off > 0; off >>= 1) sq += __shfl_down(sq, off, 64);
    if (lane == 0) {
        hq[row] = 0.5f * sq;
        sumexp[row] = 0.0f;
    }
}

// Kernel 2: barrier-free, LDS-free fp8 Gram + exp + row-sum scatter.
// 128x128 block tile, each wave a 64x64 quadrant (4x4 16x16 accs).
// Fragments loaded straight from panel-layout muf8 (coalesced 1KB
// wave-loads already in MFMA layout), 2-buffer register pipeline at
// PREFETCH DISTANCE 2 (consume cp, then overwrite that buffer with cp+2;
// distance 3 regressed — R11: +64 VGPR live state past the sweet spot),
// XCD-aware swizzle (each XCD's 128 blocks cover a 16x8 tile region ->
// ~1.5 MB working set, L2-resident). NO fences (agent-scope release emits
// buffer_wbl2 -> L2 eviction poison, proven R2+R9).
// expo[i,j] = (G_ij - hq_i - hq_j)/s <= ~0 (max on diag = 0): plain
// sum-of-exp, no online max needed.
__global__ __launch_bounds__(256) void gram_lse_kernel(const unsigned char* __restrict__ muf8,
                                                       const float* __restrict__ hq,
                                                       const float* __restrict__ sigma,
                                                       float* __restrict__ sumexp) {
    const int t = threadIdx.x;
    const int wave = t >> 6;
    const int lane = t & 63;
    const int r16 = lane & 15;
    const int quad = lane >> 4;

    // XCD swizzle: x = XCD, s = slot; region = 16 tile-rows x 8 tile-cols.
    const int bswz = blockIdx.x;
    const int x = bswz & 7, s = bswz >> 3;
    const int by = (x >> 2) * 16 + (s & 15);
    const int bx = (x & 3) * 8 + (s >> 4);

    const int row0 = by * TILE + (wave >> 1) * 64;
    const int col0 = bx * TILE + (wave & 1) * 64;

    // Per-fragment base pointers (16B units): panel p, cp=0, this lane.
    const longx2* base = (const longx2*)muf8;
    const longx2* pA[4];
    const longx2* pB[4];
    #pragma unroll
    for (int i = 0; i < 4; i++)
        pA[i] = base + ((size_t)(row0 / 16 + i) * 8) * 64 + lane;
    #pragma unroll
    for (int j = 0; j < 4; j++)
        pB[j] = base + ((size_t)(col0 / 16 + j) * 8) * 64 + lane;

    floatx4 acc[4][4];
    #pragma unroll
    for (int i = 0; i < 4; i++)
        #pragma unroll
        for (int j = 0; j < 4; j++) {
            floatx4 z = {0.f, 0.f, 0.f, 0.f};
            acc[i][j] = z;
        }

    // 2-buffer register pipeline, prefetch distance 2 (cp stride = 64 units).
    longx2 fa[2][4], fb[2][4];
    #pragma unroll
    for (int i = 0; i < 4; i++) fa[0][i] = pA[i][0];
    #pragma unroll
    for (int j = 0; j < 4; j++) fb[0][j] = pB[j][0];
    #pragma unroll
    for (int i = 0; i < 4; i++) fa[1][i] = pA[i][64];
    #pragma unroll
    for (int j = 0; j < 4; j++) fb[1][j] = pB[j][64];

    #pragma unroll
    for (int cp = 0; cp < NCP; cp++) {
        const int cur = cp & 1;
        #pragma unroll
        for (int i = 0; i < 4; i++)
            #pragma unroll
            for (int j = 0; j < 4; j++)
                acc[i][j] = __builtin_amdgcn_mfma_f32_16x16x32_fp8_fp8(fa[cur][i][0], fb[cur][j][0], acc[i][j], 0, 0, 0);
        #pragma unroll
        for (int i = 0; i < 4; i++)
            #pragma unroll
            for (int j = 0; j < 4; j++)
                acc[i][j] = __builtin_amdgcn_mfma_f32_16x16x32_fp8_fp8(fa[cur][i][1], fb[cur][j][1], acc[i][j], 0, 0, 0);
        if (cp + 2 < NCP) {
            #pragma unroll
            for (int i = 0; i < 4; i++) fa[cur][i] = pA[i][(cp + 2) * 64];
            #pragma unroll
            for (int j = 0; j < 4; j++) fb[cur][j] = pB[j][(cp + 2) * 64];
        }
    }

    // Epilogue. C/D layout (m89-verified, dtype-independent): col = lane&15,
    // row = quad*4 + reg.
    const float inv_s = 1.0f / sigma[0];
    float hqc[4];
    #pragma unroll
    for (int j = 0; j < 4; j++) hqc[j] = hq[col0 + j * 16 + r16];

    #pragma unroll
    for (int i = 0; i < 4; i++) {
        #pragma unroll
        for (int r = 0; r < 4; r++) {
            const int row = row0 + i * 16 + quad * 4 + r;
            const float hr = hq[row];
            float rs = 0.0f;
            #pragma unroll
            for (int j = 0; j < 4; j++)
                rs += __expf((acc[i][j][r] - hr - hqc[j]) * inv_s);
            rs += __shfl_xor(rs, 1, 64);
            rs += __shfl_xor(rs, 2, 64);
            rs += __shfl_xor(rs, 4, 64);
            rs += __shfl_xor(rs, 8, 64);
            if (r16 == 0) atomicAdd(&sumexp[row], rs);
        }
    }
}

// Kernel 3: entropy = D/2 + ln(B) + (D/2)ln(2*pi*s) - mean_i log(sumexp_i)
__global__ __launch_bounds__(1024) void finalize_kernel(const float* __restrict__ sumexp,
                                                        const float* __restrict__ sigma,
                                                        float* __restrict__ out) {
    const int t = threadIdx.x;
    float local = 0.0f;
    for (int i = t; i < NB; i += 1024) local += logf(sumexp[i]);
    #pragma unroll
    for (int off = 32; off > 0; off >>= 1) local += __shfl_down(local, off, 64);
    __shared__ float red[16];
    if ((t & 63) == 0) red[t >> 6] = local;
    __syncthreads();
    if (t == 0) {
        double tot = 0.0;
        #pragma unroll
        for (int i = 0; i < 16; i++) tot += (double)red[i];
        const double s = (double)sigma[0];
        const double ent = (double)(ND / 2)
                         + log((double)NB)
                         + (double)(ND / 2) * log(2.0 * M_PI * s)
                         - tot / (double)NB;
        out[0] = (float)ent;
        out[1] = (float)ent;
    }
}

extern "C" void kernel_launch(void* const* d_in, const int* in_sizes, int n_in,
                              void* d_out, int out_size, void* d_ws, size_t ws_size,
                              hipStream_t stream) {
    (void)in_sizes; (void)n_in; (void)out_size; (void)ws_size;
    const float* codewords = (const float*)d_in[1];  // d_in[0] = info (unused)
    const float* sigma     = (const float*)d_in[2];
    float* out = (float*)d_out;

    char* ws = (char*)d_ws;
    unsigned char* muf8 = (unsigned char*)ws;                      // 2 MB (fp8 panels)
    float* hq     = (float*)(ws + (size_t)NB * ND);                // 16 KB
    float* sumexp = hq + NB;                                       // 16 KB

    prep_kernel<<<NB / 4, 256, 0, stream>>>(codewords, muf8, hq, sumexp);
    gram_lse_kernel<<<1024, 256, 0, stream>>>(muf8, hq, sigma, sumexp);
    finalize_kernel<<<1, 1024, 0, stream>>>(sumexp, sigma, out);
}